// Round 1
// baseline (188186.218 us; speedup 1.0000x reference)
//
#include <hip/hip_runtime.h>
#include <cstdint>
#include <cstddef>

#define Bn 64
#define Sn 128
#define Hn 4096
#define Gn 16384   // 4H
#define H2n 8192   // 2H
#define KC 32

// ---------------- lengths ----------------
__global__ void len_kernel(const int* __restrict__ masks, float* __restrict__ lenf) {
  int b = blockIdx.x;
  int s = threadIdx.x;            // 64 threads = 1 wave
  int v0 = (masks[b * Sn + s] == 0) ? 1 : 0;
  int v1 = (masks[b * Sn + 64 + s] == 0) ? 1 : 0;
  unsigned long long m0 = __ballot(v0);
  unsigned long long m1 = __ballot(v1);
  if (s == 0) lenf[b] = (float)(__popcll(m0) + __popcll(m1));
}

// ---------------- zero init (h0, c, P) ----------------
__global__ void zero_hcp(float* __restrict__ h0, float* __restrict__ c,
                         float* __restrict__ Pt) {
  int idx = blockIdx.x * 256 + threadIdx.x;  // 262144 total
  h0[idx] = 0.f; c[idx] = 0.f; Pt[idx] = 0.f;
}

// ---------------- generic C = A * W^T, 64(m) x 64(n) tile ----------------
// lanes = n columns; W chunk staged via LDS (coalesced); A rows (M small) read
// with wave-uniform addresses -> scalar loads (SGPR operand in FMA).
__global__ __launch_bounds__(256, 2)
void gemmNT64(const float* __restrict__ Abase, int lda,
              const int* __restrict__ gather, long akoff,
              const float* __restrict__ Wbase, int ldw, long wkoff,
              int klen,
              const float* __restrict__ bias0, const float* __restrict__ bias1,
              float* __restrict__ Cbase, int ldc, long csplit)
{
  __shared__ float Ws[64][KC + 4];          // pad 36: conflict-free b128 col reads
  int tid  = threadIdx.x;
  int lane = tid & 63;
  int wv   = __builtin_amdgcn_readfirstlane(tid >> 6);   // wave id, provably uniform
  int n0   = blockIdx.x * 64;
  int m0   = blockIdx.y * 64;
  long ak  = akoff + (long)blockIdx.z * klen;
  long wk  = wkoff + (long)blockIdx.z * klen;
  size_t co = (size_t)blockIdx.z * (size_t)csplit;

  float acc[16];
#pragma unroll
  for (int i = 0; i < 16; i++) acc[i] = 0.f;

  for (int k0 = 0; k0 < klen; k0 += KC) {
    __syncthreads();
    {
      int row = tid >> 3;
      int c4  = (tid & 7) * 4;
#pragma unroll
      for (int p = 0; p < 2; p++) {
        const float* src = Wbase + (size_t)(n0 + row + p * 32) * (size_t)ldw
                                 + (size_t)(wk + k0 + c4);
        *(float4*)&Ws[row + p * 32][c4] = *(const float4*)src;
      }
    }
    __syncthreads();
    float wreg[KC];
#pragma unroll
    for (int i = 0; i < KC; i += 4) {
      float4 v = *(float4*)&Ws[lane][i];
      wreg[i] = v.x; wreg[i+1] = v.y; wreg[i+2] = v.z; wreg[i+3] = v.w;
    }
#pragma unroll
    for (int r = 0; r < 16; r++) {
      int m = m0 + wv * 16 + r;                       // uniform
      int arow = gather ? gather[m] : m;              // scalar load, uniform
      const float* ap = Abase + (size_t)arow * (size_t)lda + (size_t)(ak + k0);
#pragma unroll
      for (int i = 0; i < KC; i += 4) {
        float4 a = *(const float4*)(ap + i);          // uniform addr -> s_load_dwordx4
        acc[r] = fmaf(a.x, wreg[i],   acc[r]);
        acc[r] = fmaf(a.y, wreg[i+1], acc[r]);
        acc[r] = fmaf(a.z, wreg[i+2], acc[r]);
        acc[r] = fmaf(a.w, wreg[i+3], acc[r]);
      }
    }
  }
  float bval = 0.f;
  if (bias0) bval += bias0[n0 + lane];
  if (bias1) bval += bias1[n0 + lane];
#pragma unroll
  for (int r = 0; r < 16; r++) {
    int m = m0 + wv * 16 + r;
    Cbase[co + (size_t)m * (size_t)ldc + (size_t)(n0 + lane)] = acc[r] + bval;
  }
}

// ---------------- one LSTM time step (fused gates GEMM + cell update) ----------
// grid 256 blocks: block handles 16 j-indices x 4 gates (64 W_hh rows) x all 64 b.
__global__ __launch_bounds__(256, 2)
void lstm_step(const float* __restrict__ hin, float* __restrict__ hout,
               float* __restrict__ cbuf, float* __restrict__ P,
               const float* __restrict__ Whh,
               const float* __restrict__ xA, const float* __restrict__ xqb,
               const int* __restrict__ masks, int t)
{
  __shared__ float Ws[64][KC + 4];
  __shared__ float Gs[64][65];     // [b][n_local] gate preacts
  int tid  = threadIdx.x;
  int lane = tid & 63;
  int wv   = __builtin_amdgcn_readfirstlane(tid >> 6);
  int j0   = blockIdx.x * 16;
  int gate = lane >> 4;
  int jj   = lane & 15;

  float acc[16];
#pragma unroll
  for (int i = 0; i < 16; i++) acc[i] = 0.f;

  for (int k0 = 0; k0 < Hn; k0 += KC) {
    __syncthreads();
    {
      int row = tid >> 3;
      int c4  = (tid & 7) * 4;
#pragma unroll
      for (int p = 0; p < 2; p++) {
        int rl = row + p * 32;
        int rg = rl >> 4, rj = rl & 15;
        const float* src = Whh + (size_t)(rg * Hn + j0 + rj) * (size_t)Hn
                               + (size_t)(k0 + c4);
        *(float4*)&Ws[rl][c4] = *(const float4*)src;
      }
    }
    __syncthreads();
    float wreg[KC];
#pragma unroll
    for (int i = 0; i < KC; i += 4) {
      float4 v = *(float4*)&Ws[lane][i];
      wreg[i] = v.x; wreg[i+1] = v.y; wreg[i+2] = v.z; wreg[i+3] = v.w;
    }
#pragma unroll
    for (int r = 0; r < 16; r++) {
      int b = wv * 16 + r;                      // uniform
      const float* hp = hin + (size_t)b * Hn + k0;
#pragma unroll
      for (int i = 0; i < KC; i += 4) {
        float4 a = *(const float4*)(hp + i);    // uniform -> s_load
        acc[r] = fmaf(a.x, wreg[i],   acc[r]);
        acc[r] = fmaf(a.y, wreg[i+1], acc[r]);
        acc[r] = fmaf(a.z, wreg[i+2], acc[r]);
        acc[r] = fmaf(a.w, wreg[i+3], acc[r]);
      }
    }
  }

  int gidx = gate * Hn + j0 + jj;   // index in 16384-wide [i|f|g|o] gate vector
#pragma unroll
  for (int r = 0; r < 16; r++) {
    int b = wv * 16 + r;
    float pre = acc[r] + xA[((size_t)b * Sn + t) * Gn + gidx]
                       + xqb[(size_t)b * Gn + gidx];
    Gs[b][lane] = pre;
  }
  __syncthreads();

#pragma unroll
  for (int p = 0; p < 4; p++) {
    int b = (tid >> 4) + p * 16;
    int j = tid & 15;
    float iv = Gs[b][j];
    float fv = Gs[b][16 + j];
    float gv = Gs[b][32 + j];
    float ov = Gs[b][48 + j];
    float ig = 1.f / (1.f + expf(-iv));
    float fg = 1.f / (1.f + expf(-fv));
    float og = 1.f / (1.f + expf(-ov));
    size_t hidx = (size_t)b * Hn + j0 + j;
    float cv = cbuf[hidx];
    float cn = fg * cv + ig * tanhf(gv);
    float hn = og * tanhf(cn);
    bool valid = (masks[b * Sn + t] == 0);
    float hold = hin[hidx];
    hout[hidx] = valid ? hn : hold;
    if (valid) {
      cbuf[hidx] = cn;
      P[hidx] += hn;
    }
  }
}

// ---------------- data = [Q, P/len, Q-P, Q*P] ----------------
__global__ void databuild(const float* __restrict__ emb, const int* __restrict__ questions,
                          const float* __restrict__ P, const float* __restrict__ lenf,
                          float* __restrict__ data)
{
  int idx = blockIdx.x * 256 + threadIdx.x;   // 262144
  int b = idx >> 12;
  int k = idx & 4095;
  float q = emb[(size_t)questions[b] * Hn + k];
  float p = P[idx] / lenf[b];
  float* d = data + (size_t)b * Gn;
  d[k]          = q;
  d[Hn + k]     = p;
  d[2 * Hn + k] = q - p;
  d[3 * Hn + k] = q * p;
}

// ---------------- reduce hid partials, score, focal BCE ----------------
__global__ void loss_kernel(const float* __restrict__ hidp, const float* __restrict__ b1,
                            const float* __restrict__ W2, const float* __restrict__ b2,
                            const int* __restrict__ labels, float* __restrict__ out)
{
  __shared__ float sc[64];
  __shared__ float bces[64];
  int tid = threadIdx.x;
  int b = tid >> 2;
  int q = tid & 3;
  float sum = 0.f;
  for (int j = q; j < 1024; j += 4) {
    float v = b1[j];
#pragma unroll
    for (int ks = 0; ks < 8; ks++) v += hidp[((size_t)ks * 64 + b) * 1024 + j];
    float hid = v > 0.f ? v : 0.01f * v;     // leaky_relu(0.01)
    sum += hid * W2[j];
  }
  sum += __shfl_down(sum, 1, 4);
  sum += __shfl_down(sum, 2, 4);
  if (q == 0) sc[b] = sum;
  __syncthreads();
  if (tid < 64) {
    float pre = sc[tid] + b2[0];
    float s = 1.f / (1.f + expf(-pre));
    float eps = 1e-7f;
    float p = fminf(fmaxf(s, eps), 1.f - eps);
    float y = (float)labels[tid];
    float bce = -(y * logf(p) + (1.f - y) * logf(1.f - p));
    float pt = expf(-bce);
    float om = 1.f - pt;
    bces[tid] = om * om * bce;
  }
  __syncthreads();
  if (tid == 0) {
    float tsum = 0.f;
    for (int i = 0; i < 64; i++) tsum += bces[i];
    out[0] = tsum;
  }
}

extern "C" void kernel_launch(void* const* d_in, const int* in_sizes, int n_in,
                              void* d_out, int out_size, void* d_ws, size_t ws_size,
                              hipStream_t stream) {
  (void)in_sizes; (void)n_in; (void)out_size; (void)ws_size;
  const int*   questions = (const int*)d_in[0];
  const int*   contexts  = (const int*)d_in[1];
  const int*   masks     = (const int*)d_in[2];
  const int*   labels    = (const int*)d_in[3];
  const float* emb       = (const float*)d_in[4];
  const float* W_ih      = (const float*)d_in[5];
  const float* W_hh      = (const float*)d_in[6];
  const float* b_ih      = (const float*)d_in[7];
  const float* b_hh      = (const float*)d_in[8];
  const float* W1        = (const float*)d_in[9];
  const float* b1        = (const float*)d_in[10];
  const float* W2        = (const float*)d_in[11];
  const float* b2        = (const float*)d_in[12];
  float* out = (float*)d_out;

  // workspace carve-up (floats). Requires ~552 MB of d_ws.
  float* xA   = (float*)d_ws;                          // 8192*16384
  float* xqb  = xA  + (size_t)8192 * 16384;            // 64*16384
  float* h0   = xqb + (size_t)64 * 16384;              // 64*4096
  float* h1   = h0  + (size_t)64 * 4096;
  float* cbuf = h1  + (size_t)64 * 4096;
  float* P    = cbuf+ (size_t)64 * 4096;
  float* lenf = P   + (size_t)64 * 4096;               // 64
  float* data = lenf+ 64;                              // 64*16384
  float* hidp = data+ (size_t)64 * 16384;              // 8*64*1024

  zero_hcp<<<1024, 256, 0, stream>>>(h0, cbuf, P);
  len_kernel<<<64, 64, 0, stream>>>(masks, lenf);

  // xqb[b][g] = Q_b . W_ih[g, 4096:8192] + b_ih[g] + b_hh[g]
  gemmNT64<<<dim3(256, 1, 1), 256, 0, stream>>>(
      emb, Hn, questions, 0, W_ih, H2n, 4096, Hn, b_ih, b_hh, xqb, Gn, 0);

  // xA[(b,s)][g] = A_{b,s} . W_ih[g, 0:4096]
  gemmNT64<<<dim3(256, 128, 1), 256, 0, stream>>>(
      emb, Hn, contexts, 0, W_ih, H2n, 0, Hn, nullptr, nullptr, xA, Gn, 0);

  for (int t = 0; t < Sn; t++) {
    const float* hi = (t & 1) ? h1 : h0;
    float*       ho = (t & 1) ? h0 : h1;
    lstm_step<<<256, 256, 0, stream>>>(hi, ho, cbuf, P, W_hh, xA, xqb, masks, t);
  }

  databuild<<<1024, 256, 0, stream>>>(emb, questions, P, lenf, data);

  // hidp[ks][b][n] = partial (data . W1^T) over K-slice ks*2048..+2048
  gemmNT64<<<dim3(16, 1, 8), 256, 0, stream>>>(
      data, Gn, nullptr, 0, W1, Gn, 0, 2048, nullptr, nullptr, hidp, 1024, 64 * 1024);

  loss_kernel<<<1, 256, 0, stream>>>(hidp, b1, W2, b2, labels, out);
}

// Round 2
// 8243.089 us; speedup vs baseline: 22.8296x; 22.8296x over previous
//
#include <hip/hip_runtime.h>
#include <cstdint>
#include <cstddef>

typedef __attribute__((ext_vector_type(8))) short short8;
typedef __attribute__((ext_vector_type(4))) float f32x4;
typedef unsigned short ushort_t;

#define DEV static __device__ __forceinline__

DEV unsigned short f2bf(float f) {
  unsigned u = __float_as_uint(f);
  u += 0x7FFFu + ((u >> 16) & 1u);           // RNE
  return (unsigned short)(u >> 16);
}
DEV float bf2f(unsigned short h) { return __uint_as_float(((unsigned)h) << 16); }
DEV float sigm(float x) { return 1.f / (1.f + __expf(-x)); }
DEV float tanh_f(float x) {
  float a = fabsf(x);
  float e = __expf(-2.f * a);
  float t = (1.f - e) / (1.f + e);
  return x < 0.f ? -t : t;
}
DEV void gl2lds(const void* g, void* l) {
  __builtin_amdgcn_global_load_lds(
      (const __attribute__((address_space(1))) unsigned int*)g,
      (__attribute__((address_space(3))) unsigned int*)l, 16, 0, 0);
}
DEV f32x4 mfma16(short8 a, short8 b, f32x4 c) {
  return __builtin_amdgcn_mfma_f32_16x16x32_bf16(a, b, c, 0, 0, 0);
}

// ---------------- lengths ----------------
__global__ void len_kernel(const int* __restrict__ masks, float* __restrict__ lenf) {
  int b = blockIdx.x;
  int s = threadIdx.x;
  int v0 = (masks[b * 128 + s] == 0) ? 1 : 0;
  int v1 = (masks[b * 128 + 64 + s] == 0) ? 1 : 0;
  unsigned long long m0 = __ballot(v0);
  unsigned long long m1 = __ballot(v1);
  if (s == 0) lenf[b] = (float)(__popcll(m0) + __popcll(m1));
}

// ---------------- fp32 -> bf16 row-window convert ----------------
__global__ void cvt_w(const float* __restrict__ src, ushort_t* __restrict__ dst,
                      long n4, int c4shift, int src_ld, int c0) {
  long i4 = (long)blockIdx.x * 256 + threadIdx.x;
  if (i4 >= n4) return;
  long row = i4 >> c4shift;
  int k4 = (int)(i4 & ((1L << c4shift) - 1)) * 4;
  const float* s = src + (size_t)row * src_ld + c0 + k4;
  float4 v = *(const float4*)s;
  ushort_t* d = dst + (size_t)i4 * 4;
  d[0] = f2bf(v.x); d[1] = f2bf(v.y); d[2] = f2bf(v.z); d[3] = f2bf(v.w);
}

// ---------------- gather rows of emb -> bf16 ----------------
__global__ void cvt_gather(const float* __restrict__ emb, const int* __restrict__ idx,
                           ushort_t* __restrict__ dst, long n4) {
  long i4 = (long)blockIdx.x * 256 + threadIdx.x;
  if (i4 >= n4) return;
  int r = (int)(i4 >> 10);
  int k4 = (int)(i4 & 1023) * 4;
  int row = idx[r];
  float4 v = *(const float4*)(emb + (size_t)row * 4096 + k4);
  ushort_t* d = dst + (size_t)i4 * 4;
  d[0] = f2bf(v.x); d[1] = f2bf(v.y); d[2] = f2bf(v.z); d[3] = f2bf(v.w);
}

// ---------------- big GEMM: C[8192x16384] = A[8192x4096] . W[16384x4096]^T (bf16) --
// m97 recipe: 128x128 tile, 4x4 of 16x16x32 MFMA per wave, BK=64,
// global_load_lds(16B), XOR-swizzled LDS, 2-barrier K-loop.
__global__ __launch_bounds__(256, 2)
void gemm_big(const ushort_t* __restrict__ Abf, const ushort_t* __restrict__ Wbf,
              ushort_t* __restrict__ Cbf) {
  __shared__ __align__(16) char sm[32768];   // A tile [128][64]bf16 sw; B at +16384
  const int tid = threadIdx.x;
  const int lane = tid & 63;
  const int w = __builtin_amdgcn_readfirstlane(tid >> 6);
  const int m0 = blockIdx.x * 128;
  const int n0 = blockIdx.y * 128;

  // staging: 16 insts each for A and B; inst i = w*4+j covers rows i*8..i*8+7
  const ushort_t* gA[4];
  const ushort_t* gB[4];
#pragma unroll
  for (int j = 0; j < 4; j++) {
    int i = w * 4 + j;
    int row = i * 8 + (lane >> 3);
    int u = (lane & 7) ^ (row & 7);          // logical 16B-unit (swizzled)
    gA[j] = Abf + (size_t)(m0 + row) * 4096 + u * 8;
    gB[j] = Wbf + (size_t)(n0 + row) * 4096 + u * 8;
  }
  char* ldsA = sm;
  char* ldsB = sm + 16384;

  // fragment LDS byte offsets (loop-invariant)
  int fA[2][4], fB[2][4];
#pragma unroll
  for (int t = 0; t < 2; t++) {
#pragma unroll
    for (int tl = 0; tl < 4; tl++) {
      int rowA = (w & 1) * 64 + tl * 16 + (lane & 15);
      int up = (t * 4 + (lane >> 4)) ^ (rowA & 7);
      fA[t][tl] = rowA * 128 + up * 16;
      int rowB = (w >> 1) * 64 + tl * 16 + (lane & 15);
      int upB = (t * 4 + (lane >> 4)) ^ (rowB & 7);
      fB[t][tl] = 16384 + rowB * 128 + upB * 16;
    }
  }

  f32x4 acc[4][4];
#pragma unroll
  for (int a = 0; a < 4; a++)
#pragma unroll
    for (int b = 0; b < 4; b++) acc[a][b] = {0.f, 0.f, 0.f, 0.f};

  for (int kc = 0; kc < 4096; kc += 64) {
#pragma unroll
    for (int j = 0; j < 4; j++) {
      gl2lds(gA[j] + kc, ldsA + (w * 4 + j) * 1024);
      gl2lds(gB[j] + kc, ldsB + (w * 4 + j) * 1024);
    }
    __syncthreads();                          // compiler adds vmcnt(0) drain
#pragma unroll
    for (int t = 0; t < 2; t++) {
      short8 av[4], bv[4];
#pragma unroll
      for (int q2 = 0; q2 < 4; q2++) av[q2] = *(const short8*)(sm + fA[t][q2]);
#pragma unroll
      for (int q2 = 0; q2 < 4; q2++) bv[q2] = *(const short8*)(sm + fB[t][q2]);
#pragma unroll
      for (int tm = 0; tm < 4; tm++)
#pragma unroll
        for (int tn = 0; tn < 4; tn++)
          acc[tm][tn] = mfma16(av[tm], bv[tn], acc[tm][tn]);
    }
    __syncthreads();                          // readers done before next stage
  }

  const int q = lane >> 4, col = lane & 15;
#pragma unroll
  for (int tm = 0; tm < 4; tm++)
#pragma unroll
    for (int tn = 0; tn < 4; tn++)
#pragma unroll
      for (int r = 0; r < 4; r++) {
        int m = m0 + (w & 1) * 64 + tm * 16 + q * 4 + r;
        int n = n0 + (w >> 1) * 64 + tn * 16 + col;
        Cbf[(size_t)m * 16384 + n] = f2bf(acc[tm][tn][r]);
      }
}

// ---------------- small-M GEMM: C[64xN] = A[64xK] . W[N xK]^T  (fp32 out) -------
// wave w: rows 16w..16w+15, all 64 n (4 tiles). B double-buffered via global_load_lds.
__global__ __launch_bounds__(256, 2)
void gemm64(const ushort_t* __restrict__ A, int lda,
            const ushort_t* __restrict__ Wb, int ldw, int klen,
            const float* __restrict__ bias0, const float* __restrict__ bias1,
            float* __restrict__ Cf, int ldc) {
  __shared__ __align__(16) char sm[65536];   // 2 x 32KB B buffers [64][256]bf16 sw
  const int tid = threadIdx.x;
  const int lane = tid & 63;
  const int w = __builtin_amdgcn_readfirstlane(tid >> 6);
  const int n0 = blockIdx.x * 64;
  const int kbase = blockIdx.z * klen;
  const size_t co = (size_t)blockIdx.z * 64 * ldc;

  const ushort_t* gW[8];
  int ldsOff[8];
#pragma unroll
  for (int j = 0; j < 8; j++) {
    int i = w * 8 + j;
    int row = i * 2 + (lane >> 5);
    int up = lane & 31;
    int u = (up & ~7) | ((up & 7) ^ (row & 7));
    gW[j] = Wb + (size_t)(n0 + row) * ldw + kbase + u * 8;
    ldsOff[j] = i * 1024;
  }
  const ushort_t* aBase = A + (size_t)(w * 16 + (lane & 15)) * lda + kbase + (lane >> 4) * 8;

  f32x4 acc[4];
#pragma unroll
  for (int g = 0; g < 4; g++) acc[g] = {0.f, 0.f, 0.f, 0.f};

  const int nch = klen >> 8;
#pragma unroll
  for (int j = 0; j < 8; j++) gl2lds(gW[j], sm + ldsOff[j]);   // prologue chunk 0

  for (int ck = 0; ck < nch; ck++) {
    __syncthreads();                         // vmcnt(0): waits current buf only
    int cur = (ck & 1) * 32768;
    if (ck + 1 < nch) {
      int nxt = ((ck + 1) & 1) * 32768;
      int koff = (ck + 1) * 256;
#pragma unroll
      for (int j = 0; j < 8; j++) gl2lds(gW[j] + koff, sm + nxt + ldsOff[j]);
    }
    const ushort_t* aP = aBase + ck * 256;
#pragma unroll
    for (int t = 0; t < 8; t++) {
      short8 av = *(const short8*)(aP + t * 32);
#pragma unroll
      for (int g = 0; g < 4; g++) {
        int row = g * 16 + (lane & 15);
        int u = t * 4 + (lane >> 4);
        int up = (u & ~7) | ((u & 7) ^ (lane & 7));
        short8 bv = *(const short8*)(sm + cur + row * 512 + up * 16);
        acc[g] = mfma16(av, bv, acc[g]);
      }
    }
  }

  const int q = lane >> 4, jj = lane & 15;
#pragma unroll
  for (int g = 0; g < 4; g++)
#pragma unroll
    for (int r = 0; r < 4; r++) {
      int m = w * 16 + q * 4 + r;
      int n = n0 + g * 16 + jj;
      float v = acc[g][r];
      if (bias0) v += bias0[n];
      if (bias1) v += bias1[n];
      Cf[co + (size_t)m * ldc + n] = v;
    }
}

// ---------------- fused LSTM step: gates GEMM + cell update ----------------
// block: 16 j's x 4 gates x 64 b. n-tiles == gates -> in-register epilogue.
__global__ __launch_bounds__(256, 2)
void lstm_step(const ushort_t* __restrict__ hin, ushort_t* __restrict__ hout,
               float* __restrict__ cb, float* __restrict__ Pb,
               const ushort_t* __restrict__ Whh,
               const ushort_t* __restrict__ xA, const float* __restrict__ xqb,
               const int* __restrict__ masks, int t) {
  __shared__ __align__(16) char sm[65536];
  const int tid = threadIdx.x;
  const int lane = tid & 63;
  const int w = __builtin_amdgcn_readfirstlane(tid >> 6);
  const int j0 = blockIdx.x * 16;

  const ushort_t* gW[8];
  int ldsOff[8];
#pragma unroll
  for (int j = 0; j < 8; j++) {
    int i = w * 8 + j;
    int row = i * 2 + (lane >> 5);            // n_local 0..63
    int up = lane & 31;
    int u = (up & ~7) | ((up & 7) ^ (row & 7));
    int wrow = (row >> 4) * 4096 + j0 + (row & 15);   // gate-major W_hh row
    gW[j] = Whh + (size_t)wrow * 4096 + u * 8;
    ldsOff[j] = i * 1024;
  }
  const ushort_t* aBase = hin + (size_t)(w * 16 + (lane & 15)) * 4096 + (lane >> 4) * 8;

  f32x4 acc[4];
#pragma unroll
  for (int g = 0; g < 4; g++) acc[g] = {0.f, 0.f, 0.f, 0.f};

#pragma unroll
  for (int j = 0; j < 8; j++) gl2lds(gW[j], sm + ldsOff[j]);

  for (int ck = 0; ck < 16; ck++) {
    __syncthreads();
    int cur = (ck & 1) * 32768;
    if (ck + 1 < 16) {
      int nxt = ((ck + 1) & 1) * 32768;
      int koff = (ck + 1) * 256;
#pragma unroll
      for (int j = 0; j < 8; j++) gl2lds(gW[j] + koff, sm + nxt + ldsOff[j]);
    }
    const ushort_t* aP = aBase + ck * 256;
#pragma unroll
    for (int ts = 0; ts < 8; ts++) {
      short8 av = *(const short8*)(aP + ts * 32);
#pragma unroll
      for (int g = 0; g < 4; g++) {
        int row = g * 16 + (lane & 15);
        int u = ts * 4 + (lane >> 4);
        int up = (u & ~7) | ((u & 7) ^ (lane & 7));
        short8 bv = *(const short8*)(sm + cur + row * 512 + up * 16);
        acc[g] = mfma16(av, bv, acc[g]);
      }
    }
  }

  // in-register fused cell update: lane holds i,f,g,o for (b, j0+jj)
  const int q = lane >> 4, jj = lane & 15;
#pragma unroll
  for (int r = 0; r < 4; r++) {
    int b = w * 16 + q * 4 + r;
    bool valid = (masks[b * 128 + t] == 0);
    size_t xrow = ((size_t)b * 128 + t) * 16384 + j0 + jj;
    size_t qrow = (size_t)b * 16384 + j0 + jj;
    float pi = acc[0][r] + bf2f(xA[xrow])         + xqb[qrow];
    float pf = acc[1][r] + bf2f(xA[xrow + 4096])  + xqb[qrow + 4096];
    float pg = acc[2][r] + bf2f(xA[xrow + 8192])  + xqb[qrow + 8192];
    float po = acc[3][r] + bf2f(xA[xrow + 12288]) + xqb[qrow + 12288];
    float ig = sigm(pi), fg = sigm(pf), gv = tanh_f(pg), og = sigm(po);
    size_t hi = (size_t)b * 4096 + j0 + jj;
    float cv = cb[hi];
    float cn = fg * cv + ig * gv;
    float hn = og * tanh_f(cn);
    if (valid) {
      cb[hi] = cn;
      Pb[hi] += hn;
      hout[hi] = f2bf(hn);
    } else {
      hout[hi] = hin[hi];
    }
  }
}

// ---------------- data = [Q, P/len, Q-P, Q*P] (bf16) ----------------
__global__ void databuild(const float* __restrict__ emb, const int* __restrict__ questions,
                          const float* __restrict__ P, const float* __restrict__ lenf,
                          ushort_t* __restrict__ databf) {
  int idx = blockIdx.x * 256 + threadIdx.x;   // 262144
  int b = idx >> 12, k = idx & 4095;
  float qv = emb[(size_t)questions[b] * 4096 + k];
  float pv = P[idx] / lenf[b];
  ushort_t* d = databf + (size_t)b * 16384;
  d[k] = f2bf(qv);
  d[4096 + k] = f2bf(pv);
  d[8192 + k] = f2bf(qv - pv);
  d[12288 + k] = f2bf(qv * pv);
}

// ---------------- reduce hid partials, score, focal BCE ----------------
__global__ void loss_kernel(const float* __restrict__ hidp, const float* __restrict__ b1,
                            const float* __restrict__ W2, const float* __restrict__ b2,
                            const int* __restrict__ labels, float* __restrict__ out) {
  __shared__ float sc[64];
  __shared__ float bces[64];
  int tid = threadIdx.x;
  int b = tid >> 2;
  int q = tid & 3;
  float sum = 0.f;
  for (int j = q; j < 1024; j += 4) {
    float v = b1[j];
#pragma unroll
    for (int ks = 0; ks < 8; ks++) v += hidp[((size_t)ks * 64 + b) * 1024 + j];
    float hid = v > 0.f ? v : 0.01f * v;
    sum += hid * W2[j];
  }
  sum += __shfl_down(sum, 1, 4);
  sum += __shfl_down(sum, 2, 4);
  if (q == 0) sc[b] = sum;
  __syncthreads();
  if (tid < 64) {
    float pre = sc[tid] + b2[0];
    float s = 1.f / (1.f + expf(-pre));
    float eps = 1e-7f;
    float p = fminf(fmaxf(s, eps), 1.f - eps);
    float y = (float)labels[tid];
    float bce = -(y * logf(p) + (1.f - y) * logf(1.f - p));
    float pt = expf(-bce);
    float om = 1.f - pt;
    bces[tid] = om * om * bce;
  }
  __syncthreads();
  if (tid == 0) {
    float tsum = 0.f;
    for (int i = 0; i < 64; i++) tsum += bces[i];
    out[0] = tsum;
  }
}

extern "C" void kernel_launch(void* const* d_in, const int* in_sizes, int n_in,
                              void* d_out, int out_size, void* d_ws, size_t ws_size,
                              hipStream_t stream) {
  (void)in_sizes; (void)n_in; (void)out_size; (void)ws_size;
  const int*   questions = (const int*)d_in[0];
  const int*   contexts  = (const int*)d_in[1];
  const int*   masks     = (const int*)d_in[2];
  const int*   labels    = (const int*)d_in[3];
  const float* emb       = (const float*)d_in[4];
  const float* W_ih      = (const float*)d_in[5];
  const float* W_hh      = (const float*)d_in[6];
  const float* b_ih      = (const float*)d_in[7];
  const float* b_hh      = (const float*)d_in[8];
  const float* W1        = (const float*)d_in[9];
  const float* b1        = (const float*)d_in[10];
  const float* W2        = (const float*)d_in[11];
  const float* b2        = (const float*)d_in[12];
  float* out = (float*)d_out;

  char* ws = (char*)d_ws;
  ushort_t* bufW   = (ushort_t*)ws;                       // 128 MB shared W buffer
  ushort_t* xAbf   = (ushort_t*)(ws + 0x08000000);        // 256 MB
  ushort_t* Abf    = (ushort_t*)(ws + 0x18000000);        // 64 MB
  ushort_t* Qbf    = (ushort_t*)(ws + 0x1C000000);        // 512 KB
  float*    xqb    = (float*)(ws + 0x1C080000);           // 4 MB
  ushort_t* hbf0   = (ushort_t*)(ws + 0x1C480000);        // 512 KB
  ushort_t* hbf1   = (ushort_t*)(ws + 0x1C500000);        // 512 KB
  float*    cbuf   = (float*)(ws + 0x1C580000);           // 1 MB
  float*    Pbuf   = (float*)(ws + 0x1C680000);           // 1 MB
  float*    lenf   = (float*)(ws + 0x1C780000);           // 256 B
  ushort_t* databf = (ushort_t*)(ws + 0x1C781000);        // 2 MB
  float*    hidp   = (float*)(ws + 0x1C981000);           // 2 MB   (end ~481 MB)

  hipMemsetAsync(cbuf, 0, (size_t)64 * 4096 * 4, stream);
  hipMemsetAsync(Pbuf, 0, (size_t)64 * 4096 * 4, stream);
  hipMemsetAsync(hbf0, 0, (size_t)64 * 4096 * 2, stream);

  len_kernel<<<64, 64, 0, stream>>>(masks, lenf);
  cvt_gather<<<32768, 256, 0, stream>>>(emb, contexts, Abf, 8192L * 1024);
  cvt_gather<<<256, 256, 0, stream>>>(emb, questions, Qbf, 64L * 1024);

  // W_ih Q-half -> bufW; xqb = Q . WihQ^T + b_ih + b_hh
  cvt_w<<<65536, 256, 0, stream>>>(W_ih, bufW, 16384L * 1024, 10, 8192, 4096);
  gemm64<<<dim3(256, 1, 1), 256, 0, stream>>>(Qbf, 4096, bufW, 4096, 4096,
                                              b_ih, b_hh, xqb, 16384);

  // W_ih A-half -> bufW; xA = A . WihA^T
  cvt_w<<<65536, 256, 0, stream>>>(W_ih, bufW, 16384L * 1024, 10, 8192, 0);
  gemm_big<<<dim3(64, 128), 256, 0, stream>>>(Abf, bufW, xAbf);

  // W_hh -> bufW; 128 fused LSTM steps
  cvt_w<<<65536, 256, 0, stream>>>(W_hh, bufW, 16384L * 1024, 10, 4096, 0);
  for (int t = 0; t < 128; t++) {
    const ushort_t* hi = (t & 1) ? hbf1 : hbf0;
    ushort_t*       ho = (t & 1) ? hbf0 : hbf1;
    lstm_step<<<256, 256, 0, stream>>>(hi, ho, cbuf, Pbuf, bufW, xAbf, xqb, masks, t);
  }

  databuild<<<1024, 256, 0, stream>>>(emb, questions, Pbuf, lenf, databf);

  // W1 -> bufW; hidp[z][64][1024] partials over K-slices of 2048
  cvt_w<<<16384, 256, 0, stream>>>(W1, bufW, 1024L * 4096, 12, 16384, 0);
  gemm64<<<dim3(16, 1, 8), 256, 0, stream>>>(databf, 16384, bufW, 16384, 2048,
                                             nullptr, nullptr, hidp, 1024);

  loss_kernel<<<1, 256, 0, stream>>>(hidp, b1, W2, b2, labels, out);
}